// Round 1
// baseline (18948.352 us; speedup 1.0000x reference)
//
#include <hip/hip_runtime.h>
#include <hip/hip_bf16.h>
#include <cstddef>

// Problem dims (fixed)
#define BB 256
#define CC 512
#define SS 128      // FH*FW = 8*16
#define HH 512
#define VV 64
#define LL 24       // sequence length; steps = 23

__device__ __forceinline__ float wave_sum(float v) {
#pragma unroll
    for (int off = 32; off > 0; off >>= 1) v += __shfl_xor(v, off);
    return v;
}
__device__ __forceinline__ float wave_max(float v) {
#pragma unroll
    for (int off = 32; off > 0; off >>= 1) v = fmaxf(v, __shfl_xor(v, off));
    return v;
}
__device__ __forceinline__ float sigm(float x) { return 1.0f / (1.0f + expf(-x)); }

// ---------------------------------------------------------------------------
// init: broadcast init_state into h0/h1, zero loss accumulators
__global__ __launch_bounds__(256) void init_kernel(const float* __restrict__ init_state,
                                                   float* __restrict__ h0,
                                                   float* __restrict__ h1,
                                                   float* __restrict__ acc) {
    int idx = blockIdx.x * 256 + threadIdx.x;
    if (idx < BB * HH) {
        h0[idx] = init_state[idx & (HH - 1)];
        h1[idx] = init_state[HH + (idx & (HH - 1))];
    }
    if (idx < 2) acc[idx] = 0.0f;
}

// ---------------------------------------------------------------------------
// Ws[m,n] = sum_k enc[b,k,s]*W[n,k] + bias[n],  m = b*128+s. M=32768,N=512,K=512
__global__ __launch_bounds__(256) void ws_gemm_kernel(const float* __restrict__ enc,
                                                      const float* __restrict__ W,
                                                      const float* __restrict__ bias,
                                                      float* __restrict__ Ws) {
    __shared__ float at[16][64];
    __shared__ float bt[16][68];
    int tid = threadIdx.x;
    int m0 = blockIdx.x * 64;
    int n0 = blockIdx.y * 64;
    int b = m0 >> 7, s0 = m0 & (SS - 1);
    const float* encb = enc + (size_t)b * CC * SS;
    float acc[4][4] = {};
    int tm = tid >> 4, tn = tid & 15;
    for (int k0 = 0; k0 < CC; k0 += 16) {
#pragma unroll
        for (int i = 0; i < 4; i++) {
            int idx = tid + i * 256;
            int kk = idx >> 6, mm = idx & 63;
            at[kk][mm] = encb[(size_t)(k0 + kk) * SS + s0 + mm];
        }
#pragma unroll
        for (int i = 0; i < 4; i++) {
            int idx = tid + i * 256;
            int nn = idx >> 4, kk = idx & 15;
            bt[kk][nn] = W[(size_t)(n0 + nn) * CC + k0 + kk];
        }
        __syncthreads();
#pragma unroll
        for (int kk = 0; kk < 16; kk++) {
            float4 av = *(const float4*)&at[kk][tm * 4];
            float4 bv = *(const float4*)&bt[kk][tn * 4];
            float a4[4] = {av.x, av.y, av.z, av.w};
            float b4[4] = {bv.x, bv.y, bv.z, bv.w};
#pragma unroll
            for (int i = 0; i < 4; i++)
#pragma unroll
                for (int j = 0; j < 4; j++) acc[i][j] += a4[i] * b4[j];
        }
        __syncthreads();
    }
#pragma unroll
    for (int i = 0; i < 4; i++) {
        int m = m0 + tm * 4 + i;
        float4 o;
        o.x = acc[i][0] + bias[n0 + tn * 4 + 0];
        o.y = acc[i][1] + bias[n0 + tn * 4 + 1];
        o.z = acc[i][2] + bias[n0 + tn * 4 + 2];
        o.w = acc[i][3] + bias[n0 + tn * 4 + 3];
        *(float4*)&Ws[(size_t)m * HH + n0 + tn * 4] = o;
    }
}

// ---------------------------------------------------------------------------
// Generic linear: out[m,n] = act( sum_k A[m,k]*W[n,k] + bias[n] )
// A[m,k]: k<512 -> xA[m*512+k]; (HASB && k>=512) -> xB[m*512+k-512]
template <int KX, bool HASB, bool RELU>
__global__ __launch_bounds__(256) void linear_kernel(const float* __restrict__ xA,
                                                     const float* __restrict__ xB,
                                                     const float* __restrict__ W,
                                                     const float* __restrict__ bias,
                                                     float* __restrict__ out1,
                                                     float* __restrict__ out2,
                                                     int ostride) {
    __shared__ float xs[32][17];
    __shared__ float wsh[32][68];
    int tid = threadIdx.x;
    int m0 = blockIdx.x * 16;
    int n0 = blockIdx.y * 64;
    int nn = tid & 63;
    int mq = tid >> 6;  // 0..3
    float acc[4] = {};
    for (int k0 = 0; k0 < KX; k0 += 32) {
#pragma unroll
        for (int i = 0; i < 2; i++) {
            int idx = tid + i * 256;
            int mm = idx >> 5, kk = idx & 31;
            int m = m0 + mm, k = k0 + kk;
            float v;
            if (HASB && k >= 512) v = xB[(size_t)m * 512 + (k - 512)];
            else v = xA[(size_t)m * 512 + k];
            xs[kk][mm] = v;
        }
#pragma unroll
        for (int i = 0; i < 8; i++) {
            int idx = tid + i * 256;
            int wn = idx >> 5, kk = idx & 31;
            wsh[kk][wn] = W[(size_t)(n0 + wn) * KX + k0 + kk];
        }
        __syncthreads();
#pragma unroll
        for (int kk = 0; kk < 32; kk++) {
            float wv = wsh[kk][nn];
#pragma unroll
            for (int i = 0; i < 4; i++) acc[i] += xs[kk][mq * 4 + i] * wv;
        }
        __syncthreads();
    }
    int n = n0 + nn;
#pragma unroll
    for (int i = 0; i < 4; i++) {
        int m = m0 + mq * 4 + i;
        float v = acc[i] + bias[n];
        if (RELU) v = fmaxf(v, 0.0f);
        out1[(size_t)m * ostride + n] = v;
        if (out2) out2[(size_t)m * ostride + n] = v;
    }
}

// ---------------------------------------------------------------------------
// GRU cell, fused gi+gh+gates. Tile 16 (b) x 64 (h). grid (16,8)
template <bool GATHER>
__global__ __launch_bounds__(256) void gru_kernel(const float* __restrict__ xA,
                                                  const float* __restrict__ embed_w,
                                                  const int* __restrict__ seq, int t,
                                                  const float* __restrict__ h_prev,
                                                  const float* __restrict__ wih,
                                                  const float* __restrict__ whh,
                                                  const float* __restrict__ bih,
                                                  const float* __restrict__ bhh,
                                                  float* __restrict__ h_out) {
    const int KX = GATHER ? 1024 : 512;
    __shared__ float xs[32][17];
    __shared__ float ws3[3][32][68];
    int tid = threadIdx.x;
    int m0 = blockIdx.x * 16;
    int n0 = blockIdx.y * 64;
    int nn = tid & 63;
    int mq = tid >> 6;
    float agi[3][4] = {};
    float agh[3][4] = {};
    // Phase A: gi = x @ wih.T
    for (int k0 = 0; k0 < KX; k0 += 32) {
#pragma unroll
        for (int i = 0; i < 2; i++) {
            int idx = tid + i * 256;
            int mm = idx >> 5, kk = idx & 31;
            int m = m0 + mm, k = k0 + kk;
            float v;
            if (GATHER && k >= 512) {
                int row = seq[m * LL + t];
                v = embed_w[(size_t)row * HH + (k - 512)];
            } else {
                v = xA[(size_t)m * 512 + k];
            }
            xs[kk][mm] = v;
        }
#pragma unroll
        for (int g = 0; g < 3; g++)
#pragma unroll
            for (int i = 0; i < 8; i++) {
                int idx = tid + i * 256;
                int wn = idx >> 5, kk = idx & 31;
                ws3[g][kk][wn] = wih[(size_t)(g * 512 + n0 + wn) * KX + k0 + kk];
            }
        __syncthreads();
#pragma unroll
        for (int kk = 0; kk < 32; kk++) {
            float xv[4];
#pragma unroll
            for (int i = 0; i < 4; i++) xv[i] = xs[kk][mq * 4 + i];
#pragma unroll
            for (int g = 0; g < 3; g++) {
                float wv = ws3[g][kk][nn];
#pragma unroll
                for (int i = 0; i < 4; i++) agi[g][i] += xv[i] * wv;
            }
        }
        __syncthreads();
    }
    // Phase B: gh = h_prev @ whh.T (K=512)
    for (int k0 = 0; k0 < 512; k0 += 32) {
#pragma unroll
        for (int i = 0; i < 2; i++) {
            int idx = tid + i * 256;
            int mm = idx >> 5, kk = idx & 31;
            xs[kk][mm] = h_prev[(size_t)(m0 + mm) * HH + k0 + kk];
        }
#pragma unroll
        for (int g = 0; g < 3; g++)
#pragma unroll
            for (int i = 0; i < 8; i++) {
                int idx = tid + i * 256;
                int wn = idx >> 5, kk = idx & 31;
                ws3[g][kk][wn] = whh[(size_t)(g * 512 + n0 + wn) * 512 + k0 + kk];
            }
        __syncthreads();
#pragma unroll
        for (int kk = 0; kk < 32; kk++) {
            float xv[4];
#pragma unroll
            for (int i = 0; i < 4; i++) xv[i] = xs[kk][mq * 4 + i];
#pragma unroll
            for (int g = 0; g < 3; g++) {
                float wv = ws3[g][kk][nn];
#pragma unroll
                for (int i = 0; i < 4; i++) agh[g][i] += xv[i] * wv;
            }
        }
        __syncthreads();
    }
    int n = n0 + nn;
#pragma unroll
    for (int i = 0; i < 4; i++) {
        int m = m0 + mq * 4 + i;
        float r = sigm(agi[0][i] + bih[n] + agh[0][i] + bhh[n]);
        float z = sigm(agi[1][i] + bih[512 + n] + agh[1][i] + bhh[512 + n]);
        float nact = tanhf(agi[2][i] + bih[1024 + n] + r * (agh[2][i] + bhh[1024 + n]));
        float hp = h_prev[(size_t)m * HH + n];
        h_out[(size_t)m * HH + n] = (1.0f - z) * nact + z * hp;
    }
}

// ---------------------------------------------------------------------------
// Attention: scores over Ws + u, softmax, ctx. One block per b.
__global__ __launch_bounds__(256) void attn_kernel(const float* __restrict__ u,
                                                   const float* __restrict__ Ws,
                                                   const float* __restrict__ enc,
                                                   const float* __restrict__ vw,
                                                   float* __restrict__ ctx) {
    int b = blockIdx.x;
    int tid = threadIdx.x;
    int lane = tid & 63, wave = tid >> 6;
    __shared__ float sc[SS];
    float ur[8], vr[8];
#pragma unroll
    for (int j = 0; j < 8; j++) {
        ur[j] = u[(size_t)b * HH + lane + j * 64];
        vr[j] = vw[lane + j * 64];
    }
    const float* wsb = Ws + (size_t)b * SS * HH;
    for (int s = wave; s < SS; s += 4) {
        const float* row = wsb + (size_t)s * HH;
        float p = 0.0f;
#pragma unroll
        for (int j = 0; j < 8; j++) {
            float e = row[lane + j * 64] + ur[j];
            e = fmaxf(e, 0.0f);
            p += e * vr[j];
        }
        p = wave_sum(p);
        if (lane == 0) sc[s] = p;
    }
    __syncthreads();
    if (wave == 0) {
        float v0 = sc[lane], v1 = sc[lane + 64];
        float m = wave_max(fmaxf(v0, v1));
        float e0 = expf(v0 - m), e1 = expf(v1 - m);
        float ssum = wave_sum(e0 + e1);
        float inv = 1.0f / ssum;
        sc[lane] = e0 * inv;
        sc[lane + 64] = e1 * inv;
    }
    __syncthreads();
    float alo = sc[lane], ahi = sc[lane + 64];
    const float* eb = enc + (size_t)b * CC * SS;
    for (int cc = 0; cc < 128; cc++) {
        int c = wave * 128 + cc;
        float p = alo * eb[(size_t)c * SS + lane] + ahi * eb[(size_t)c * SS + lane + 64];
        p = wave_sum(p);
        if (lane == 0) ctx[(size_t)b * CC + c] = p;
    }
}

// ---------------------------------------------------------------------------
// NLL over logits (t*256+b, 64). 368 blocks x 64 threads, 16 items each.
__global__ __launch_bounds__(64) void nll_kernel(const float* __restrict__ logits,
                                                 const int* __restrict__ seq,
                                                 float* __restrict__ acc) {
    int lane = threadIdx.x;
    float lsum = 0.0f, lcnt = 0.0f;
    for (int i = 0; i < 16; i++) {
        int item = blockIdx.x * 16 + i;
        int t = item >> 8, b = item & 255;
        float v = logits[(size_t)item * VV + lane];
        float m = wave_max(v);
        float e = expf(v - m);
        float s = wave_sum(e);
        int label = seq[b * LL + t + 1];
        float vl = __shfl(v, label);
        if (lane == 0 && label > 0) {
            lsum += -(vl - m - logf(s));
            lcnt += 1.0f;
        }
    }
    if (lane == 0) {
        atomicAdd(&acc[0], lsum);
        atomicAdd(&acc[1], lcnt);
    }
}

__global__ void final_kernel(const float* __restrict__ acc, float* __restrict__ out) {
    if (threadIdx.x == 0) out[0] = acc[0] / acc[1];
}

// ---------------------------------------------------------------------------
extern "C" void kernel_launch(void* const* d_in, const int* in_sizes, int n_in,
                              void* d_out, int out_size, void* d_ws, size_t ws_size,
                              hipStream_t stream) {
    const float* enc        = (const float*)d_in[0];
    const int*   seq        = (const int*)d_in[1];
    const float* embed_w    = (const float*)d_in[3];
    const float* init_state = (const float*)d_in[4];
    const float* attn_W_w   = (const float*)d_in[5];
    const float* attn_W_b   = (const float*)d_in[6];
    const float* attn_U_w   = (const float*)d_in[7];
    const float* attn_U_b   = (const float*)d_in[8];
    const float* attn_v_w   = (const float*)d_in[9];
    const float* fc_w       = (const float*)d_in[11];
    const float* fc_b       = (const float*)d_in[12];
    const float* cls_w      = (const float*)d_in[13];
    const float* cls_b      = (const float*)d_in[14];
    const float* g0_wih     = (const float*)d_in[15];
    const float* g0_whh     = (const float*)d_in[16];
    const float* g0_bih     = (const float*)d_in[17];
    const float* g0_bhh     = (const float*)d_in[18];
    const float* g1_wih     = (const float*)d_in[19];
    const float* g1_whh     = (const float*)d_in[20];
    const float* g1_bih     = (const float*)d_in[21];
    const float* g1_bhh     = (const float*)d_in[22];
    float* out = (float*)d_out;

    float* ws = (float*)d_ws;
    size_t o = 0;
    float* Ws     = ws + o; o += (size_t)BB * SS * HH;       // 16.78M
    float* ys     = ws + o; o += (size_t)(LL - 1) * BB * HH; // 3.01M
    float* h0a    = ws + o; o += (size_t)BB * HH;
    float* h0b    = ws + o; o += (size_t)BB * HH;
    float* h1a    = ws + o; o += (size_t)BB * HH;
    float* h1b    = ws + o; o += (size_t)BB * HH;
    float* y      = ws + o; o += (size_t)BB * HH;
    float* u      = ws + o; o += (size_t)BB * HH;
    float* ctx    = ws + o; o += (size_t)BB * CC;
    float* logits = ws + o; o += (size_t)(LL - 1) * BB * VV;
    float* acc    = ws + o; o += 256;

    init_kernel<<<512, 256, 0, stream>>>(init_state, h0a, h1a, acc);
    ws_gemm_kernel<<<dim3(512, 8), 256, 0, stream>>>(enc, attn_W_w, attn_W_b, Ws);

    // y0 = out_proj(attn(h1), h1), h1 = broadcast init_state[1]
    linear_kernel<512, false, false><<<dim3(16, 8), 256, 0, stream>>>(
        h1a, nullptr, attn_U_w, attn_U_b, u, nullptr, HH);
    attn_kernel<<<BB, 256, 0, stream>>>(u, Ws, enc, attn_v_w, ctx);
    linear_kernel<1024, true, true><<<dim3(16, 8), 256, 0, stream>>>(
        ctx, h1a, fc_w, fc_b, y, nullptr, HH);

    float* h0_in = h0a; float* h0_out = h0b;
    float* h1_in = h1a; float* h1_out = h1b;
    for (int t = 0; t < LL - 1; t++) {
        gru_kernel<true><<<dim3(16, 8), 256, 0, stream>>>(
            y, embed_w, seq, t, h0_in, g0_wih, g0_whh, g0_bih, g0_bhh, h0_out);
        gru_kernel<false><<<dim3(16, 8), 256, 0, stream>>>(
            h0_out, nullptr, nullptr, 0, h1_in, g1_wih, g1_whh, g1_bih, g1_bhh, h1_out);
        linear_kernel<512, false, false><<<dim3(16, 8), 256, 0, stream>>>(
            h1_out, nullptr, attn_U_w, attn_U_b, u, nullptr, HH);
        attn_kernel<<<BB, 256, 0, stream>>>(u, Ws, enc, attn_v_w, ctx);
        linear_kernel<1024, true, true><<<dim3(16, 8), 256, 0, stream>>>(
            ctx, h1_out, fc_w, fc_b, y, ys + (size_t)t * BB * HH, HH);
        float* tmp;
        tmp = h0_in; h0_in = h0_out; h0_out = tmp;
        tmp = h1_in; h1_in = h1_out; h1_out = tmp;
    }

    // logits = ys @ cls_w.T + cls_b : M=5888, N=64, K=512
    linear_kernel<512, false, false><<<dim3(368, 1), 256, 0, stream>>>(
        ys, nullptr, cls_w, cls_b, logits, nullptr, VV);
    nll_kernel<<<368, 64, 0, stream>>>(logits, seq, acc);
    final_kernel<<<1, 1, 0, stream>>>(acc, out);
}

// Round 2
// 2968.696 us; speedup vs baseline: 6.3827x; 6.3827x over previous
//
#include <hip/hip_runtime.h>
#include <hip/hip_bf16.h>
#include <cstddef>

// Problem dims (fixed)
#define BB 256
#define CC 512
#define SS 128      // FH*FW = 8*16
#define HH 512
#define VV 64
#define LL 24       // sequence length; steps = 23

__device__ __forceinline__ float wave_sum(float v) {
#pragma unroll
    for (int off = 32; off > 0; off >>= 1) v += __shfl_xor(v, off);
    return v;
}
__device__ __forceinline__ float wave_max(float v) {
#pragma unroll
    for (int off = 32; off > 0; off >>= 1) v = fmaxf(v, __shfl_xor(v, off));
    return v;
}
__device__ __forceinline__ float sigm(float x) { return 1.0f / (1.0f + expf(-x)); }

// ---------------------------------------------------------------------------
// init: broadcast init_state into h0/h1, zero loss accumulators
__global__ __launch_bounds__(256) void init_kernel(const float* __restrict__ init_state,
                                                   float* __restrict__ h0,
                                                   float* __restrict__ h1,
                                                   float* __restrict__ acc) {
    int idx = blockIdx.x * 256 + threadIdx.x;
    if (idx < BB * HH) {
        h0[idx] = init_state[idx & (HH - 1)];
        h1[idx] = init_state[HH + (idx & (HH - 1))];
    }
    if (idx < 2) acc[idx] = 0.0f;
}

// ---------------------------------------------------------------------------
// Pre-gather embeddings for all steps: xall[(t*256+m)*512 + :] = embed_w[seq[m][t]]
__global__ __launch_bounds__(128) void gather_kernel(const float* __restrict__ embed_w,
                                                     const int* __restrict__ seq,
                                                     float* __restrict__ xall) {
    int item = blockIdx.x;           // t*256 + m
    int t = item >> 8, m = item & 255;
    int row = seq[m * LL + t];
    const float4* src = (const float4*)(embed_w + (size_t)row * HH);
    float4* dst = (float4*)(xall + (size_t)item * HH);
    dst[threadIdx.x] = src[threadIdx.x];
}

// ---------------------------------------------------------------------------
// Ws[m,n] = sum_k enc[b,k,s]*W[n,k] + bias[n],  m = b*128+s. M=32768,N=512,K=512
__global__ __launch_bounds__(256) void ws_gemm_kernel(const float* __restrict__ enc,
                                                      const float* __restrict__ W,
                                                      const float* __restrict__ bias,
                                                      float* __restrict__ Ws) {
    __shared__ float at[16][64];
    __shared__ float bt[16][68];
    int tid = threadIdx.x;
    int m0 = blockIdx.x * 64;
    int n0 = blockIdx.y * 64;
    int b = m0 >> 7, s0 = m0 & (SS - 1);
    const float* encb = enc + (size_t)b * CC * SS;
    float acc[4][4] = {};
    int tm = tid >> 4, tn = tid & 15;
    for (int k0 = 0; k0 < CC; k0 += 16) {
#pragma unroll
        for (int i = 0; i < 4; i++) {
            int idx = tid + i * 256;
            int kk = idx >> 6, mm = idx & 63;
            at[kk][mm] = encb[(size_t)(k0 + kk) * SS + s0 + mm];
        }
#pragma unroll
        for (int i = 0; i < 4; i++) {
            int idx = tid + i * 256;
            int nn = idx >> 4, kk = idx & 15;
            bt[kk][nn] = W[(size_t)(n0 + nn) * CC + k0 + kk];
        }
        __syncthreads();
#pragma unroll
        for (int kk = 0; kk < 16; kk++) {
            float4 av = *(const float4*)&at[kk][tm * 4];
            float4 bv = *(const float4*)&bt[kk][tn * 4];
            float a4[4] = {av.x, av.y, av.z, av.w};
            float b4[4] = {bv.x, bv.y, bv.z, bv.w};
#pragma unroll
            for (int i = 0; i < 4; i++)
#pragma unroll
                for (int j = 0; j < 4; j++) acc[i][j] += a4[i] * b4[j];
        }
        __syncthreads();
    }
#pragma unroll
    for (int i = 0; i < 4; i++) {
        int m = m0 + tm * 4 + i;
        float4 o;
        o.x = acc[i][0] + bias[n0 + tn * 4 + 0];
        o.y = acc[i][1] + bias[n0 + tn * 4 + 1];
        o.z = acc[i][2] + bias[n0 + tn * 4 + 2];
        o.w = acc[i][3] + bias[n0 + tn * 4 + 3];
        *(float4*)&Ws[(size_t)m * HH + n0 + tn * 4] = o;
    }
}

// ---------------------------------------------------------------------------
// Generic split-K GEMM. Block: 64m x 64n, K=256 per z-chunk. 256 threads, 4x4/thread.
// X row stride is always 512 (all activations). W row stride per z.
// Writes partials P[(z*M + m)*N + n] (no bias).
struct SplitkArgs {
    const float* x[6];   // pre-offset by k-chunk
    const float* w[6];   // pre-offset by k-chunk
    int wstride[6];
};

__global__ __launch_bounds__(256) void gemm_splitk(SplitkArgs args, int M, int N,
                                                   float* __restrict__ P) {
    __shared__ float xs[32][68];
    __shared__ float wsm[32][68];
    int tid = threadIdx.x;
    int m0 = blockIdx.x * 64;
    int n0 = blockIdx.y * 64;
    int z = blockIdx.z;
    const float* X = args.x[z];
    const float* W = args.w[z];
    int wst = args.wstride[z];
    int tm = tid >> 4, tn = tid & 15;
    float acc[4][4] = {};
    for (int k0 = 0; k0 < 256; k0 += 32) {
#pragma unroll
        for (int i = 0; i < 2; i++) {
            int idx = tid + i * 256;           // 0..511
            int mm = idx >> 3, k4 = idx & 7;
            float4 v = *(const float4*)(X + (size_t)(m0 + mm) * 512 + k0 + k4 * 4);
            xs[k4 * 4 + 0][mm] = v.x;
            xs[k4 * 4 + 1][mm] = v.y;
            xs[k4 * 4 + 2][mm] = v.z;
            xs[k4 * 4 + 3][mm] = v.w;
        }
#pragma unroll
        for (int i = 0; i < 2; i++) {
            int idx = tid + i * 256;
            int nn = idx >> 3, k4 = idx & 7;
            float4 v = *(const float4*)(W + (size_t)(n0 + nn) * wst + k0 + k4 * 4);
            wsm[k4 * 4 + 0][nn] = v.x;
            wsm[k4 * 4 + 1][nn] = v.y;
            wsm[k4 * 4 + 2][nn] = v.z;
            wsm[k4 * 4 + 3][nn] = v.w;
        }
        __syncthreads();
#pragma unroll
        for (int kk = 0; kk < 32; kk++) {
            float4 av = *(const float4*)&xs[kk][tm * 4];
            float4 bv = *(const float4*)&wsm[kk][tn * 4];
            float a4[4] = {av.x, av.y, av.z, av.w};
            float b4[4] = {bv.x, bv.y, bv.z, bv.w};
#pragma unroll
            for (int i = 0; i < 4; i++)
#pragma unroll
                for (int j = 0; j < 4; j++) acc[i][j] += a4[i] * b4[j];
        }
        __syncthreads();
    }
#pragma unroll
    for (int i = 0; i < 4; i++) {
        int m = m0 + tm * 4 + i;
        *(float4*)&P[((size_t)z * M + m) * N + n0 + tn * 4] =
            make_float4(acc[i][0], acc[i][1], acc[i][2], acc[i][3]);
    }
}

// ---------------------------------------------------------------------------
// GRU gate: sums split-K partials (za chunks for gi, zb for gh), applies gates.
__global__ __launch_bounds__(256) void gru_gate_kernel(const float* __restrict__ P,
                                                       int za, int zb,
                                                       const float* __restrict__ h_prev,
                                                       const float* __restrict__ bih,
                                                       const float* __restrict__ bhh,
                                                       float* __restrict__ h_out) {
    int idx = blockIdx.x * 256 + threadIdx.x;   // 0..131071
    int m = idx >> 9, n = idx & 511;
    float gir = 0, giz = 0, gin = 0, ghr = 0, ghz = 0, ghn = 0;
    for (int z = 0; z < za; z++) {
        const float* p = P + ((size_t)z * 256 + m) * 1536;
        gir += p[n]; giz += p[n + 512]; gin += p[n + 1024];
    }
    for (int z = za; z < za + zb; z++) {
        const float* p = P + ((size_t)z * 256 + m) * 1536;
        ghr += p[n]; ghz += p[n + 512]; ghn += p[n + 1024];
    }
    float r = sigm(gir + bih[n] + ghr + bhh[n]);
    float zf = sigm(giz + bih[512 + n] + ghz + bhh[512 + n]);
    float nact = tanhf(gin + bih[1024 + n] + r * (ghn + bhh[1024 + n]));
    float hp = h_prev[idx];
    h_out[idx] = (1.0f - zf) * nact + zf * hp;
}

// ---------------------------------------------------------------------------
// fc epilogue: sum 4 partials + bias + relu -> y (and optionally ys slot)
__global__ __launch_bounds__(256) void fc_fin_kernel(const float* __restrict__ P,
                                                     const float* __restrict__ bias,
                                                     float* __restrict__ y,
                                                     float* __restrict__ ys) {
    int idx = blockIdx.x * 256 + threadIdx.x;
    int n = idx & 511;
    float v = P[idx] + P[131072 + idx] + P[262144 + idx] + P[393216 + idx] + bias[n];
    v = fmaxf(v, 0.0f);
    y[idx] = v;
    if (ys) ys[idx] = v;
}

// ---------------------------------------------------------------------------
// scores[b][s] = relu(Ws[b,s,:] + u[b,:]) . v   (u = sum of 2 split-K partials + Ub)
// grid (256, 4); each wave does 8 interleaved s-chains.
__global__ __launch_bounds__(256) void scores_kernel(const float* __restrict__ Pu,
                                                     const float* __restrict__ Ub,
                                                     const float* __restrict__ Ws,
                                                     const float* __restrict__ vw,
                                                     float* __restrict__ scores) {
    int b = blockIdx.x, sg = blockIdx.y;
    int tid = threadIdx.x;
    int lane = tid & 63, wave = tid >> 6;
    int col = lane * 8;
    float4 u0 = *(const float4*)(Pu + (size_t)b * 512 + col);
    float4 u0b = *(const float4*)(Pu + (size_t)b * 512 + col + 4);
    float4 u1 = *(const float4*)(Pu + (size_t)(256 + b) * 512 + col);
    float4 u1b = *(const float4*)(Pu + (size_t)(256 + b) * 512 + col + 4);
    float4 ub = *(const float4*)(Ub + col);
    float4 ubb = *(const float4*)(Ub + col + 4);
    float ur[8] = {u0.x + u1.x + ub.x, u0.y + u1.y + ub.y, u0.z + u1.z + ub.z,
                   u0.w + u1.w + ub.w, u0b.x + u1b.x + ubb.x, u0b.y + u1b.y + ubb.y,
                   u0b.z + u1b.z + ubb.z, u0b.w + u1b.w + ubb.w};
    float4 v0 = *(const float4*)(vw + col);
    float4 v1 = *(const float4*)(vw + col + 4);
    float vr[8] = {v0.x, v0.y, v0.z, v0.w, v1.x, v1.y, v1.z, v1.w};
    int s0 = sg * 32 + wave * 8;
    float p[8];
#pragma unroll
    for (int j = 0; j < 8; j++) {
        const float* row = Ws + ((size_t)b * SS + s0 + j) * HH + col;
        float4 r0 = *(const float4*)(row);
        float4 r1 = *(const float4*)(row + 4);
        float rr[8] = {r0.x, r0.y, r0.z, r0.w, r1.x, r1.y, r1.z, r1.w};
        float acc = 0.0f;
#pragma unroll
        for (int q = 0; q < 8; q++) acc += fmaxf(rr[q] + ur[q], 0.0f) * vr[q];
        p[j] = acc;
    }
#pragma unroll
    for (int off = 32; off > 0; off >>= 1)
#pragma unroll
        for (int j = 0; j < 8; j++) p[j] += __shfl_xor(p[j], off);
    float out = p[0];
#pragma unroll
    for (int j = 1; j < 8; j++)
        if (lane == j) out = p[j];
    if (lane < 8) scores[b * SS + s0 + lane] = out;
}

// ---------------------------------------------------------------------------
// softmax over scores[b,:128] then ctx[b,c] = sum_s a[s]*enc[b,c,s]
// grid (256, 4): block handles 128 c's (32 per wave, 4 interleaved chains x 8).
__global__ __launch_bounds__(256) void ctx_kernel(const float* __restrict__ scores,
                                                  const float* __restrict__ enc,
                                                  float* __restrict__ ctx) {
    int b = blockIdx.x, cg = blockIdx.y;
    int tid = threadIdx.x;
    int lane = tid & 63, wave = tid >> 6;
    __shared__ float a[SS];
    if (wave == 0) {
        float s0 = scores[b * SS + lane];
        float s1 = scores[b * SS + 64 + lane];
        float m = wave_max(fmaxf(s0, s1));
        float e0 = expf(s0 - m), e1 = expf(s1 - m);
        float ssum = wave_sum(e0 + e1);
        float inv = 1.0f / ssum;
        a[lane] = e0 * inv;
        a[lane + 64] = e1 * inv;
    }
    __syncthreads();
    float2 av = *(const float2*)&a[lane * 2];
    const float* eb = enc + (size_t)b * CC * SS;
#pragma unroll
    for (int g = 0; g < 8; g++) {
        int cbase = cg * 128 + wave * 32 + g * 4;
        float p[4];
#pragma unroll
        for (int j = 0; j < 4; j++) {
            float2 ev = *(const float2*)(eb + (size_t)(cbase + j) * SS + lane * 2);
            p[j] = ev.x * av.x + ev.y * av.y;
        }
#pragma unroll
        for (int off = 32; off > 0; off >>= 1)
#pragma unroll
            for (int j = 0; j < 4; j++) p[j] += __shfl_xor(p[j], off);
        float out = p[0];
#pragma unroll
        for (int j = 1; j < 4; j++)
            if (lane == j) out = p[j];
        if (lane < 4) ctx[(size_t)b * CC + cbase + lane] = out;
    }
}

// ---------------------------------------------------------------------------
// NLL over logit partials P[(z*5888+item)*64 + v], z=0..1, plus cls bias.
__global__ __launch_bounds__(64) void nll_kernel(const float* __restrict__ P,
                                                 const float* __restrict__ cls_b,
                                                 const int* __restrict__ seq,
                                                 float* __restrict__ acc) {
    int lane = threadIdx.x;
    float bias = cls_b[lane];
    float lsum = 0.0f, lcnt = 0.0f;
    for (int i = 0; i < 16; i++) {
        int item = blockIdx.x * 16 + i;
        int t = item >> 8, b = item & 255;
        float v = P[(size_t)item * VV + lane] + P[(size_t)(5888 + item) * VV + lane] + bias;
        float m = wave_max(v);
        float e = expf(v - m);
        float s = wave_sum(e);
        int label = seq[b * LL + t + 1];
        float vl = __shfl(v, label);
        if (lane == 0 && label > 0) {
            lsum += -(vl - m - logf(s));
            lcnt += 1.0f;
        }
    }
    if (lane == 0) {
        atomicAdd(&acc[0], lsum);
        atomicAdd(&acc[1], lcnt);
    }
}

__global__ void final_kernel(const float* __restrict__ acc, float* __restrict__ out) {
    if (threadIdx.x == 0) out[0] = acc[0] / acc[1];
}

// ---------------------------------------------------------------------------
extern "C" void kernel_launch(void* const* d_in, const int* in_sizes, int n_in,
                              void* d_out, int out_size, void* d_ws, size_t ws_size,
                              hipStream_t stream) {
    const float* enc        = (const float*)d_in[0];
    const int*   seq        = (const int*)d_in[1];
    const float* embed_w    = (const float*)d_in[3];
    const float* init_state = (const float*)d_in[4];
    const float* attn_W_w   = (const float*)d_in[5];
    const float* attn_W_b   = (const float*)d_in[6];
    const float* attn_U_w   = (const float*)d_in[7];
    const float* attn_U_b   = (const float*)d_in[8];
    const float* attn_v_w   = (const float*)d_in[9];
    const float* fc_w       = (const float*)d_in[11];
    const float* fc_b       = (const float*)d_in[12];
    const float* cls_w      = (const float*)d_in[13];
    const float* cls_b      = (const float*)d_in[14];
    const float* g0_wih     = (const float*)d_in[15];
    const float* g0_whh     = (const float*)d_in[16];
    const float* g0_bih     = (const float*)d_in[17];
    const float* g0_bhh     = (const float*)d_in[18];
    const float* g1_wih     = (const float*)d_in[19];
    const float* g1_whh     = (const float*)d_in[20];
    const float* g1_bih     = (const float*)d_in[21];
    const float* g1_bhh     = (const float*)d_in[22];
    float* out = (float*)d_out;

    float* ws = (float*)d_ws;
    size_t o = 0;
    float* Ws     = ws + o; o += (size_t)BB * SS * HH;       // 16.78M
    float* ys     = ws + o; o += (size_t)(LL - 1) * BB * HH; // 3.01M
    float* xall   = ws + o; o += (size_t)(LL - 1) * BB * HH; // 3.01M
    float* Pgru   = ws + o; o += (size_t)6 * BB * 1536;      // 2.36M (aliased by cls)
    float* Pu     = ws + o; o += (size_t)2 * BB * HH;        // 0.26M
    float* Pfc    = ws + o; o += (size_t)4 * BB * HH;        // 0.52M
    float* h0a    = ws + o; o += (size_t)BB * HH;
    float* h0b    = ws + o; o += (size_t)BB * HH;
    float* h1a    = ws + o; o += (size_t)BB * HH;
    float* h1b    = ws + o; o += (size_t)BB * HH;
    float* y      = ws + o; o += (size_t)BB * HH;
    float* ctx    = ws + o; o += (size_t)BB * CC;
    float* scb    = ws + o; o += (size_t)BB * SS;
    float* acc    = ws + o; o += 256;
    float* Pcls   = Pgru;  // reuse (gru partials dead by epilogue)

    init_kernel<<<512, 256, 0, stream>>>(init_state, h0a, h1a, acc);
    gather_kernel<<<(LL - 1) * BB, 128, 0, stream>>>(embed_w, seq, xall);
    ws_gemm_kernel<<<dim3(512, 8), 256, 0, stream>>>(enc, attn_W_w, attn_W_b, Ws);

    auto u_args = [&](const float* h) {
        SplitkArgs a{};
        a.x[0] = h; a.x[1] = h + 256;
        a.w[0] = attn_U_w; a.w[1] = attn_U_w + 256;
        a.wstride[0] = a.wstride[1] = 512;
        return a;
    };
    auto fc_args = [&](const float* h) {
        SplitkArgs a{};
        a.x[0] = ctx; a.x[1] = ctx + 256; a.x[2] = h; a.x[3] = h + 256;
        a.w[0] = fc_w; a.w[1] = fc_w + 256; a.w[2] = fc_w + 512; a.w[3] = fc_w + 768;
        a.wstride[0] = a.wstride[1] = a.wstride[2] = a.wstride[3] = 1024;
        return a;
    };

    // ---- prologue: y0 = out_proj(attn(h1), h1)
    gemm_splitk<<<dim3(4, 8, 2), 256, 0, stream>>>(u_args(h1a), BB, HH, Pu);
    scores_kernel<<<dim3(BB, 4), 256, 0, stream>>>(Pu, attn_U_b, Ws, attn_v_w, scb);
    ctx_kernel<<<dim3(BB, 4), 256, 0, stream>>>(scb, enc, ctx);
    gemm_splitk<<<dim3(4, 8, 4), 256, 0, stream>>>(fc_args(h1a), BB, HH, Pfc);
    fc_fin_kernel<<<512, 256, 0, stream>>>(Pfc, fc_b, y, nullptr);

    float* h0_in = h0a; float* h0_out = h0b;
    float* h1_in = h1a; float* h1_out = h1b;
    for (int t = 0; t < LL - 1; t++) {
        // gru0: gi = [y, x_t] @ wih.T (K=1024, 4 chunks); gh = h0 @ whh.T (2 chunks)
        {
            const float* xt = xall + (size_t)t * BB * HH;
            SplitkArgs a{};
            a.x[0] = y;        a.x[1] = y + 256;
            a.x[2] = xt;       a.x[3] = xt + 256;
            a.x[4] = h0_in;    a.x[5] = h0_in + 256;
            a.w[0] = g0_wih;   a.w[1] = g0_wih + 256;
            a.w[2] = g0_wih + 512; a.w[3] = g0_wih + 768;
            a.w[4] = g0_whh;   a.w[5] = g0_whh + 256;
            a.wstride[0] = a.wstride[1] = a.wstride[2] = a.wstride[3] = 1024;
            a.wstride[4] = a.wstride[5] = 512;
            gemm_splitk<<<dim3(4, 24, 6), 256, 0, stream>>>(a, BB, 1536, Pgru);
        }
        gru_gate_kernel<<<512, 256, 0, stream>>>(Pgru, 4, 2, h0_in, g0_bih, g0_bhh, h0_out);
        // gru1: gi = h_l0 @ wih.T (2 chunks); gh = h1 @ whh.T (2 chunks)
        {
            SplitkArgs a{};
            a.x[0] = h0_out;   a.x[1] = h0_out + 256;
            a.x[2] = h1_in;    a.x[3] = h1_in + 256;
            a.w[0] = g1_wih;   a.w[1] = g1_wih + 256;
            a.w[2] = g1_whh;   a.w[3] = g1_whh + 256;
            a.wstride[0] = a.wstride[1] = a.wstride[2] = a.wstride[3] = 512;
            gemm_splitk<<<dim3(4, 24, 4), 256, 0, stream>>>(a, BB, 1536, Pgru);
        }
        gru_gate_kernel<<<512, 256, 0, stream>>>(Pgru, 2, 2, h1_in, g1_bih, g1_bhh, h1_out);
        // attention
        gemm_splitk<<<dim3(4, 8, 2), 256, 0, stream>>>(u_args(h1_out), BB, HH, Pu);
        scores_kernel<<<dim3(BB, 4), 256, 0, stream>>>(Pu, attn_U_b, Ws, attn_v_w, scb);
        ctx_kernel<<<dim3(BB, 4), 256, 0, stream>>>(scb, enc, ctx);
        // out_proj
        gemm_splitk<<<dim3(4, 8, 4), 256, 0, stream>>>(fc_args(h1_out), BB, HH, Pfc);
        fc_fin_kernel<<<512, 256, 0, stream>>>(Pfc, fc_b, y, ys + (size_t)t * BB * HH);
        float* tmp;
        tmp = h0_in; h0_in = h0_out; h0_out = tmp;
        tmp = h1_in; h1_in = h1_out; h1_out = tmp;
    }

    // logits partials: M=5888, N=64, K=512 (2 chunks)
    {
        SplitkArgs a{};
        a.x[0] = ys; a.x[1] = ys + 256;
        a.w[0] = cls_w; a.w[1] = cls_w + 256;
        a.wstride[0] = a.wstride[1] = 512;
        gemm_splitk<<<dim3(92, 1, 2), 256, 0, stream>>>(a, 5888, VV, Pcls);
    }
    nll_kernel<<<368, 64, 0, stream>>>(Pcls, cls_b, seq, acc);
    final_kernel<<<1, 1, 0, stream>>>(acc, out);
}

// Round 3
// 2232.110 us; speedup vs baseline: 8.4890x; 1.3300x over previous
//
#include <hip/hip_runtime.h>
#include <hip/hip_bf16.h>
#include <cstddef>

// Problem dims (fixed)
#define BB 256
#define CC 512
#define SS 128      // FH*FW = 8*16
#define HH 512
#define VV 64
#define LL 24       // sequence length; steps = 23

typedef unsigned short ush;
typedef __attribute__((ext_vector_type(8))) short short8;
typedef __attribute__((ext_vector_type(4))) float f32x4;

__device__ __forceinline__ float wave_sum(float v) {
#pragma unroll
    for (int off = 32; off > 0; off >>= 1) v += __shfl_xor(v, off);
    return v;
}
__device__ __forceinline__ float wave_max(float v) {
#pragma unroll
    for (int off = 32; off > 0; off >>= 1) v = fmaxf(v, __shfl_xor(v, off));
    return v;
}
__device__ __forceinline__ float sigm(float x) { return 1.0f / (1.0f + expf(-x)); }
__device__ __forceinline__ ush f2bf(float f) {
    unsigned u = __float_as_uint(f);
    u += 0x7FFFu + ((u >> 16) & 1u);
    return (ush)(u >> 16);
}
__device__ __forceinline__ float bf2f(ush b) {
    return __uint_as_float(((unsigned)b) << 16);
}
__device__ __forceinline__ unsigned pack2(float a, float b) {
    return (unsigned)f2bf(a) | ((unsigned)f2bf(b) << 16);
}

// ---------------------------------------------------------------------------
__global__ __launch_bounds__(256) void init_kernel(const float* __restrict__ init_state,
                                                   float* __restrict__ h0,
                                                   float* __restrict__ h1,
                                                   ush* __restrict__ h0b,
                                                   ush* __restrict__ h1b,
                                                   float* __restrict__ acc) {
    int idx = blockIdx.x * 256 + threadIdx.x;
    if (idx < BB * HH) {
        float a = init_state[idx & (HH - 1)];
        float b = init_state[HH + (idx & (HH - 1))];
        h0[idx] = a; h1[idx] = b;
        h0b[idx] = f2bf(a); h1b[idx] = f2bf(b);
    }
    if (idx < 2) acc[idx] = 0.0f;
}

// fp32 -> bf16 convert, 4 elems/thread
__global__ __launch_bounds__(256) void conv_kernel(const float* __restrict__ src,
                                                   ush* __restrict__ dst, int n4) {
    int i = blockIdx.x * 256 + threadIdx.x;
    if (i < n4) {
        float4 v = ((const float4*)src)[i];
        uint2 o;
        o.x = pack2(v.x, v.y);
        o.y = pack2(v.z, v.w);
        ((uint2*)dst)[i] = o;
    }
}

// gather embeddings -> bf16: xall[(t*256+m)*512+:]
__global__ __launch_bounds__(128) void gather_kernel(const float* __restrict__ embed_w,
                                                     const int* __restrict__ seq,
                                                     ush* __restrict__ xall) {
    int item = blockIdx.x;           // t*256 + m
    int t = item >> 8, m = item & 255;
    int row = seq[m * LL + t];
    float4 v = ((const float4*)(embed_w + (size_t)row * HH))[threadIdx.x];
    uint2 o;
    o.x = pack2(v.x, v.y);
    o.y = pack2(v.z, v.w);
    ((uint2*)(xall + (size_t)item * HH))[threadIdx.x] = o;
}

// ---------------------------------------------------------------------------
// Ws MFMA: Ws[m,n] = sum_k enc[b,k,s]*W[n,k] + bias[n], m=b*128+s, out bf16.
// A read transposed on the fly from fp32 enc. Block: 256m x 64n (4 waves x 64m).
// grid (128, 8).
__global__ __launch_bounds__(256) void ws_mfma(const float* __restrict__ enc,
                                               const ush* __restrict__ Wb,
                                               const float* __restrict__ bias,
                                               ush* __restrict__ Ws_bf) {
    int tid = threadIdx.x;
    int wave = tid >> 6, lane = tid & 63;
    int quad = lane >> 4, l16 = lane & 15;
    int m0 = blockIdx.x * 256 + wave * 64;
    int n0 = blockIdx.y * 64;
    int b = m0 >> 7;
    int s_base = m0 & 127;
    const float* eb = enc + (size_t)b * CC * SS;
    const ush* wp = Wb + (size_t)(n0 + l16) * 512 + quad * 8;
    f32x4 acc[4][4];
#pragma unroll
    for (int f = 0; f < 4; f++)
#pragma unroll
        for (int s = 0; s < 4; s++) acc[f][s] = (f32x4){0.f, 0.f, 0.f, 0.f};
    for (int k0 = 0; k0 < 512; k0 += 32) {
        short8 af[4], bfr[4];
#pragma unroll
        for (int f = 0; f < 4; f++) {
            int s = s_base + f * 16 + l16;
#pragma unroll
            for (int j = 0; j < 8; j++) {
                float v = eb[(size_t)(k0 + quad * 8 + j) * SS + s];
                af[f][j] = (short)f2bf(v);
            }
        }
#pragma unroll
        for (int s = 0; s < 4; s++)
            bfr[s] = *(const short8*)(wp + (size_t)s * 16 * 512 + k0);
#pragma unroll
        for (int f = 0; f < 4; f++)
#pragma unroll
            for (int s = 0; s < 4; s++)
                acc[f][s] = __builtin_amdgcn_mfma_f32_16x16x32_bf16(af[f], bfr[s], acc[f][s], 0, 0, 0);
    }
#pragma unroll
    for (int f = 0; f < 4; f++)
#pragma unroll
        for (int s = 0; s < 4; s++)
#pragma unroll
            for (int r = 0; r < 4; r++) {
                int m = m0 + f * 16 + quad * 4 + r;
                int n = n0 + s * 16 + l16;
                Ws_bf[(size_t)m * HH + n] = f2bf(acc[f][s][r] + bias[n]);
            }
}

// ---------------------------------------------------------------------------
// Generic split-K MFMA GEMM (bf16 in, fp32 partials out). K=512 per z-chunk.
// Block tile 64m x 64n, wave = 16m x 64n. X row stride fixed 512.
struct SkArgs {
    const ush* x[3];
    const ush* w[3];
    int wst[3];
};

__global__ __launch_bounds__(256) void mfma_gemm(SkArgs args, int N, int M,
                                                 float* __restrict__ P) {
    int tid = threadIdx.x;
    int wave = tid >> 6, lane = tid & 63;
    int quad = lane >> 4, l16 = lane & 15;
    int m0 = blockIdx.x * 64 + wave * 16;
    int n0 = blockIdx.y * 64;
    int z = blockIdx.z;
    const ush* X = args.x[z];
    const ush* W = args.w[z];
    int wst = args.wst[z];
    const ush* xp = X + (size_t)(m0 + l16) * 512 + quad * 8;
    const ush* wp = W + (size_t)(n0 + l16) * wst + quad * 8;
    f32x4 acc[4];
#pragma unroll
    for (int s = 0; s < 4; s++) acc[s] = (f32x4){0.f, 0.f, 0.f, 0.f};
    short8 a_c, b_c[4];
    a_c = *(const short8*)(xp);
#pragma unroll
    for (int s = 0; s < 4; s++) b_c[s] = *(const short8*)(wp + (size_t)s * 16 * wst);
#pragma unroll
    for (int ks = 0; ks < 16; ks++) {
        short8 a_n, b_n[4];
        if (ks < 15) {
            int k = (ks + 1) * 32;
            a_n = *(const short8*)(xp + k);
#pragma unroll
            for (int s = 0; s < 4; s++) b_n[s] = *(const short8*)(wp + (size_t)s * 16 * wst + k);
        }
#pragma unroll
        for (int s = 0; s < 4; s++)
            acc[s] = __builtin_amdgcn_mfma_f32_16x16x32_bf16(a_c, b_c[s], acc[s], 0, 0, 0);
        if (ks < 15) {
            a_c = a_n;
#pragma unroll
            for (int s = 0; s < 4; s++) b_c[s] = b_n[s];
        }
    }
#pragma unroll
    for (int s = 0; s < 4; s++)
#pragma unroll
        for (int r = 0; r < 4; r++) {
            int m = m0 + quad * 4 + r;
            int n = n0 + s * 16 + l16;
            P[((size_t)z * M + m) * N + n] = acc[s][r];
        }
}

// ---------------------------------------------------------------------------
// GRU gate: sums split-K partials (za chunks gi, zb chunks gh), applies gates.
__global__ __launch_bounds__(256) void gru_gate(const float* __restrict__ P,
                                                int za, int zb,
                                                const float* __restrict__ h_prev,
                                                const float* __restrict__ bih,
                                                const float* __restrict__ bhh,
                                                float* __restrict__ h_out,
                                                ush* __restrict__ h_out_bf) {
    int idx = blockIdx.x * 256 + threadIdx.x;   // 0..131071
    int m = idx >> 9, n = idx & 511;
    float gir = 0, giz = 0, gin = 0, ghr = 0, ghz = 0, ghn = 0;
    for (int z = 0; z < za; z++) {
        const float* p = P + ((size_t)z * 256 + m) * 1536;
        gir += p[n]; giz += p[n + 512]; gin += p[n + 1024];
    }
    for (int z = za; z < za + zb; z++) {
        const float* p = P + ((size_t)z * 256 + m) * 1536;
        ghr += p[n]; ghz += p[n + 512]; ghn += p[n + 1024];
    }
    float r = sigm(gir + bih[n] + ghr + bhh[n]);
    float zf = sigm(giz + bih[512 + n] + ghz + bhh[512 + n]);
    float nact = tanhf(gin + bih[1024 + n] + r * (ghn + bhh[1024 + n]));
    float hp = h_prev[idx];
    float ho = (1.0f - zf) * nact + zf * hp;
    h_out[idx] = ho;
    h_out_bf[idx] = f2bf(ho);
}

// ---------------------------------------------------------------------------
// fc epilogue: sum 2 partials + bias + relu -> y_bf (and optional ys_bf slot)
__global__ __launch_bounds__(256) void fc_fin(const float* __restrict__ P,
                                              const float* __restrict__ bias,
                                              ush* __restrict__ y,
                                              ush* __restrict__ ys) {
    int idx = blockIdx.x * 256 + threadIdx.x;
    int n = idx & 511;
    float v = P[idx] + P[131072 + idx] + bias[n];
    v = fmaxf(v, 0.0f);
    ush b = f2bf(v);
    y[idx] = b;
    if (ys) ys[idx] = b;
}

// ---------------------------------------------------------------------------
// Fused attention: scores (relu(Ws+u).v) -> softmax -> ctx. One block per b.
// Ws and enc in bf16; u = Pu (fp32 partial) + Ub; output ctx bf16.
__global__ __launch_bounds__(256) void attn_kernel(const float* __restrict__ Pu,
                                                   const float* __restrict__ Ub,
                                                   const float* __restrict__ vw,
                                                   const ush* __restrict__ Ws_bf,
                                                   const ush* __restrict__ enc_bf,
                                                   ush* __restrict__ ctx_bf) {
    int b = blockIdx.x;
    int tid = threadIdx.x;
    int lane = tid & 63, wave = tid >> 6;
    __shared__ float a[SS];
    int col = lane * 8;
    float4 u0 = *(const float4*)(Pu + (size_t)b * 512 + col);
    float4 u0b = *(const float4*)(Pu + (size_t)b * 512 + col + 4);
    float4 ub = *(const float4*)(Ub + col);
    float4 ubb = *(const float4*)(Ub + col + 4);
    float ur[8] = {u0.x + ub.x, u0.y + ub.y, u0.z + ub.z, u0.w + ub.w,
                   u0b.x + ubb.x, u0b.y + ubb.y, u0b.z + ubb.z, u0b.w + ubb.w};
    float4 v0 = *(const float4*)(vw + col);
    float4 v1 = *(const float4*)(vw + col + 4);
    float vr[8] = {v0.x, v0.y, v0.z, v0.w, v1.x, v1.y, v1.z, v1.w};
    const ush* wsb = Ws_bf + (size_t)b * SS * HH;
#pragma unroll
    for (int gg = 0; gg < 4; gg++) {
        int s0 = wave * 32 + gg * 8;
        float p[8];
#pragma unroll
        for (int j = 0; j < 8; j++) {
            short8 rv = *(const short8*)(wsb + (size_t)(s0 + j) * HH + col);
            float acc = 0.0f;
#pragma unroll
            for (int q = 0; q < 8; q++) {
                float e = bf2f((ush)rv[q]) + ur[q];
                acc += fmaxf(e, 0.0f) * vr[q];
            }
            p[j] = acc;
        }
#pragma unroll
        for (int off = 32; off > 0; off >>= 1)
#pragma unroll
            for (int j = 0; j < 8; j++) p[j] += __shfl_xor(p[j], off);
        float out = p[0];
#pragma unroll
        for (int j = 1; j < 8; j++)
            if (lane == j) out = p[j];
        if (lane < 8) a[s0 + lane] = out;
    }
    __syncthreads();
    if (wave == 0) {
        float s0v = a[lane], s1v = a[lane + 64];
        float m = wave_max(fmaxf(s0v, s1v));
        float e0 = expf(s0v - m), e1 = expf(s1v - m);
        float ssum = wave_sum(e0 + e1);
        float inv = 1.0f / ssum;
        a[lane] = e0 * inv;
        a[lane + 64] = e1 * inv;
    }
    __syncthreads();
    float ax = a[lane * 2], ay = a[lane * 2 + 1];
    const ush* eb = enc_bf + (size_t)b * CC * SS;
#pragma unroll
    for (int g = 0; g < 16; g++) {
        float p[8];
#pragma unroll
        for (int j = 0; j < 8; j++) {
            int c = wave * 128 + g * 8 + j;
            unsigned ev = *(const unsigned*)(eb + (size_t)c * SS + lane * 2);
            float flo = __uint_as_float(ev << 16);
            float fhi = __uint_as_float(ev & 0xFFFF0000u);
            p[j] = flo * ax + fhi * ay;
        }
#pragma unroll
        for (int off = 32; off > 0; off >>= 1)
#pragma unroll
            for (int j = 0; j < 8; j++) p[j] += __shfl_xor(p[j], off);
        float out = p[0];
#pragma unroll
        for (int j = 1; j < 8; j++)
            if (lane == j) out = p[j];
        if (lane < 8) ctx_bf[(size_t)b * CC + wave * 128 + g * 8 + lane] = f2bf(out);
    }
}

// ---------------------------------------------------------------------------
// NLL over logit partials P[item*64+v] (single chunk) + cls bias.
__global__ __launch_bounds__(64) void nll_kernel(const float* __restrict__ P,
                                                 const float* __restrict__ cls_b,
                                                 const int* __restrict__ seq,
                                                 float* __restrict__ acc) {
    int lane = threadIdx.x;
    float bias = cls_b[lane];
    float lsum = 0.0f, lcnt = 0.0f;
    for (int i = 0; i < 16; i++) {
        int item = blockIdx.x * 16 + i;
        int t = item >> 8, b = item & 255;
        float v = P[(size_t)item * VV + lane] + bias;
        float m = wave_max(v);
        float e = expf(v - m);
        float s = wave_sum(e);
        int label = seq[b * LL + t + 1];
        float vl = __shfl(v, label);
        if (lane == 0 && label > 0) {
            lsum += -(vl - m - logf(s));
            lcnt += 1.0f;
        }
    }
    if (lane == 0) {
        atomicAdd(&acc[0], lsum);
        atomicAdd(&acc[1], lcnt);
    }
}

__global__ void final_kernel(const float* __restrict__ acc, float* __restrict__ out) {
    if (threadIdx.x == 0) out[0] = acc[0] / acc[1];
}

// ---------------------------------------------------------------------------
extern "C" void kernel_launch(void* const* d_in, const int* in_sizes, int n_in,
                              void* d_out, int out_size, void* d_ws, size_t ws_size,
                              hipStream_t stream) {
    const float* enc        = (const float*)d_in[0];
    const int*   seq        = (const int*)d_in[1];
    const float* embed_w    = (const float*)d_in[3];
    const float* init_state = (const float*)d_in[4];
    const float* attn_W_w   = (const float*)d_in[5];
    const float* attn_W_b   = (const float*)d_in[6];
    const float* attn_U_w   = (const float*)d_in[7];
    const float* attn_U_b   = (const float*)d_in[8];
    const float* attn_v_w   = (const float*)d_in[9];
    const float* fc_w       = (const float*)d_in[11];
    const float* fc_b       = (const float*)d_in[12];
    const float* cls_w      = (const float*)d_in[13];
    const float* cls_b      = (const float*)d_in[14];
    const float* g0_wih     = (const float*)d_in[15];
    const float* g0_whh     = (const float*)d_in[16];
    const float* g0_bih     = (const float*)d_in[17];
    const float* g0_bhh     = (const float*)d_in[18];
    const float* g1_wih     = (const float*)d_in[19];
    const float* g1_whh     = (const float*)d_in[20];
    const float* g1_bih     = (const float*)d_in[21];
    const float* g1_bhh     = (const float*)d_in[22];
    float* out = (float*)d_out;

    float* ws = (float*)d_ws;
    size_t o = 0;
    ush* Ws_bf   = (ush*)(ws + o); o += (size_t)BB * SS * HH / 2;        // 8.4M fl
    ush* enc_bf  = (ush*)(ws + o); o += (size_t)BB * CC * SS / 2;        // 8.4M fl
    ush* ys_bf   = (ush*)(ws + o); o += (size_t)(LL - 1) * BB * HH / 2;  // 1.47M
    ush* xall_bf = (ush*)(ws + o); o += (size_t)(LL - 1) * BB * HH / 2;  // 1.47M
    // bf16 weights
    ush* wWb  = (ush*)(ws + o); o += 262144 / 2;
    ush* wU   = (ush*)(ws + o); o += 262144 / 2;
    ush* wFc  = (ush*)(ws + o); o += 524288 / 2;
    ush* wCls = (ush*)(ws + o); o += 32768 / 2;
    ush* wG0i = (ush*)(ws + o); o += 1572864 / 2;
    ush* wG0h = (ush*)(ws + o); o += 786432 / 2;
    ush* wG1i = (ush*)(ws + o); o += 786432 / 2;
    ush* wG1h = (ush*)(ws + o); o += 786432 / 2;
    // fp32 loop buffers
    float* P    = ws + o; o += (size_t)3 * BB * 1536;   // split-K partials (also cls)
    float* Pu   = ws + o; o += (size_t)BB * HH;
    float* Pfc  = ws + o; o += (size_t)2 * BB * HH;
    float* h0a  = ws + o; o += (size_t)BB * HH;
    float* h0b  = ws + o; o += (size_t)BB * HH;
    float* h1a  = ws + o; o += (size_t)BB * HH;
    float* h1b  = ws + o; o += (size_t)BB * HH;
    float* acc  = ws + o; o += 256;
    ush* h0a_bf = (ush*)(ws + o); o += (size_t)BB * HH / 2;
    ush* h0b_bf = (ush*)(ws + o); o += (size_t)BB * HH / 2;
    ush* h1a_bf = (ush*)(ws + o); o += (size_t)BB * HH / 2;
    ush* h1b_bf = (ush*)(ws + o); o += (size_t)BB * HH / 2;
    ush* y_bf   = (ush*)(ws + o); o += (size_t)BB * HH / 2;
    ush* ctx_bf = (ush*)(ws + o); o += (size_t)BB * CC / 2;
    float* Pcls = P;  // reuse after loop (5888*64 = 377K < 1.18M)

    init_kernel<<<512, 256, 0, stream>>>(init_state, h0a, h1a, h0a_bf, h1a_bf, acc);
    // weight conversions (one-time per call)
    conv_kernel<<<256, 256, 0, stream>>>(attn_W_w, wWb, 65536);
    conv_kernel<<<256, 256, 0, stream>>>(attn_U_w, wU, 65536);
    conv_kernel<<<512, 256, 0, stream>>>(fc_w, wFc, 131072);
    conv_kernel<<<32, 256, 0, stream>>>(cls_w, wCls, 8192);
    conv_kernel<<<1536, 256, 0, stream>>>(g0_wih, wG0i, 393216);
    conv_kernel<<<768, 256, 0, stream>>>(g0_whh, wG0h, 196608);
    conv_kernel<<<768, 256, 0, stream>>>(g1_wih, wG1i, 196608);
    conv_kernel<<<768, 256, 0, stream>>>(g1_whh, wG1h, 196608);
    conv_kernel<<<16384, 256, 0, stream>>>(enc, enc_bf, 4194304);
    gather_kernel<<<(LL - 1) * BB, 128, 0, stream>>>(embed_w, seq, xall_bf);
    ws_mfma<<<dim3(128, 8), 256, 0, stream>>>(enc, wWb, attn_W_b, Ws_bf);

    auto u_args = [&](const ush* h) {
        SkArgs a{};
        a.x[0] = h; a.w[0] = wU; a.wst[0] = 512;
        return a;
    };
    auto fc_args = [&](const ush* h) {
        SkArgs a{};
        a.x[0] = ctx_bf; a.x[1] = h;
        a.w[0] = wFc; a.w[1] = wFc + 512;
        a.wst[0] = a.wst[1] = 1024;
        return a;
    };

    // ---- prologue: y0 = out_proj(attn(h1), h1)
    mfma_gemm<<<dim3(4, 8, 1), 256, 0, stream>>>(u_args(h1a_bf), HH, BB, Pu);
    attn_kernel<<<BB, 256, 0, stream>>>(Pu, attn_U_b, attn_v_w, Ws_bf, enc_bf, ctx_bf);
    mfma_gemm<<<dim3(4, 8, 2), 256, 0, stream>>>(fc_args(h1a_bf), HH, BB, Pfc);
    fc_fin<<<512, 256, 0, stream>>>(Pfc, fc_b, y_bf, nullptr);

    float* h0_in = h0a; float* h0_out = h0b;
    float* h1_in = h1a; float* h1_out = h1b;
    ush* h0_in_bf = h0a_bf; ush* h0_out_bf = h0b_bf;
    ush* h1_in_bf = h1a_bf; ush* h1_out_bf = h1b_bf;
    for (int t = 0; t < LL - 1; t++) {
        // gru0: gi = [y, x_t] @ wih.T (z0,z1); gh = h0 @ whh.T (z2)
        {
            SkArgs a{};
            a.x[0] = y_bf;
            a.x[1] = xall_bf + (size_t)t * BB * HH;
            a.x[2] = h0_in_bf;
            a.w[0] = wG0i; a.w[1] = wG0i + 512; a.w[2] = wG0h;
            a.wst[0] = a.wst[1] = 1024; a.wst[2] = 512;
            mfma_gemm<<<dim3(4, 24, 3), 256, 0, stream>>>(a, 1536, BB, P);
        }
        gru_gate<<<512, 256, 0, stream>>>(P, 2, 1, h0_in, g0_bih, g0_bhh, h0_out, h0_out_bf);
        // gru1: gi = h_l0 @ wih.T (z0); gh = h1 @ whh.T (z1)
        {
            SkArgs a{};
            a.x[0] = h0_out_bf; a.x[1] = h1_in_bf;
            a.w[0] = wG1i; a.w[1] = wG1h;
            a.wst[0] = a.wst[1] = 512;
            mfma_gemm<<<dim3(4, 24, 2), 256, 0, stream>>>(a, 1536, BB, P);
        }
        gru_gate<<<512, 256, 0, stream>>>(P, 1, 1, h1_in, g1_bih, g1_bhh, h1_out, h1_out_bf);
        // attention
        mfma_gemm<<<dim3(4, 8, 1), 256, 0, stream>>>(u_args(h1_out_bf), HH, BB, Pu);
        attn_kernel<<<BB, 256, 0, stream>>>(Pu, attn_U_b, attn_v_w, Ws_bf, enc_bf, ctx_bf);
        // out_proj
        mfma_gemm<<<dim3(4, 8, 2), 256, 0, stream>>>(fc_args(h1_out_bf), HH, BB, Pfc);
        fc_fin<<<512, 256, 0, stream>>>(Pfc, fc_b, y_bf, ys_bf + (size_t)t * BB * HH);
        float* tmp;
        tmp = h0_in; h0_in = h0_out; h0_out = tmp;
        tmp = h1_in; h1_in = h1_out; h1_out = tmp;
        ush* tb;
        tb = h0_in_bf; h0_in_bf = h0_out_bf; h0_out_bf = tb;
        tb = h1_in_bf; h1_in_bf = h1_out_bf; h1_out_bf = tb;
    }

    // logits partials: M=5888, N=64, K=512 (single chunk)
    {
        SkArgs a{};
        a.x[0] = ys_bf; a.w[0] = wCls; a.wst[0] = 512;
        mfma_gemm<<<dim3(92, 1, 1), 256, 0, stream>>>(a, VV, 5888, Pcls);
    }
    nll_kernel<<<368, 64, 0, stream>>>(Pcls, cls_b, seq, acc);
    final_kernel<<<1, 1, 0, stream>>>(acc, out);
}